// Round 3
// baseline (719.330 us; speedup 1.0000x reference)
//
#include <hip/hip_runtime.h>
#include <hip/hip_bf16.h>

#define NUM_ADC_P 8
#define DENSE_L   1024
#define L_TILDE   64

typedef __attribute__((ext_vector_type(8))) short  short8;   // 8 bf16 = 4 VGPRs (MFMA A/B frag)
typedef __attribute__((ext_vector_type(4))) float  float4v;  // MFMA C/D frag

// ws layout: [0, 128 KiB) = wt bf16[64][1024]  (Wt = W^T, n-major)

// ---------------------------------------------------------------------------
// Kernel 1: Wt[n][k] = bf16(exp(-((k+1)-w_n)^2/100)), n-major.
// Full matrix, no banding: far-off entries round to (exact) bf16 zero, so the
// GEMM can run branch-free with identical numerics.
// ---------------------------------------------------------------------------
__global__ void build_w(const float* __restrict__ weight,
                        __hip_bfloat16* __restrict__ wt) {
    const int n = blockIdx.x;              // 64 blocks, one per sample position
    const float wn = weight[n];
    for (int k = threadIdx.x; k < DENSE_L; k += blockDim.x) {
        const float t = (float)(k + 1);
        const float d = t - wn;
        wt[n * DENSE_L + k] = __float2bfloat16(expf(-d * d * 0.01f));
    }
}

// ---------------------------------------------------------------------------
// 8x fp32 -> bf16 via packed HW convert (v_cvt_pk_bf16_f32 on gfx950).
// ---------------------------------------------------------------------------
__device__ __forceinline__ short8 cvt8(float4v a, float4v b) {
    union { short8 s; __hip_bfloat162 h[4]; } u;
    u.h[0] = __float22bfloat162_rn(make_float2(a[0], a[1]));
    u.h[1] = __float22bfloat162_rn(make_float2(a[2], a[3]));
    u.h[2] = __float22bfloat162_rn(make_float2(b[0], b[1]));
    u.h[3] = __float22bfloat162_rn(make_float2(b[2], b[3]));
    return u.s;
}

__device__ __forceinline__ float4v ldnt(const float* p) {
    return __builtin_nontemporal_load((const float4v*)p);
}

// ---------------------------------------------------------------------------
// Kernel 2: C[M,64] = A[M,1024] * W[1024,64], bf16 MFMA fp32-acc, no LDS.
// Wave tile 32x64 (2 m-subtiles x 4 n-subtiles of 16x16x32). Straight-line
// k-loop (no banding branches).
//
// LOAD-ORDER FIX (this round): B-fragment loads are issued BEFORE the next
// A slab's prefetch. vmcnt is FIFO — if B is issued last, consuming B forces
// s_waitcnt vmcnt(0), draining the A prefetch every iteration (the R1 flaw).
// With B first, the per-iteration wait ladder is:
//   outstanding at cvt8:  [curA x4 | B x4 | nextA x4] -> wait vmcnt(8)
//   outstanding at MFMAs: [B x4 | nextA x4]           -> wait vmcnt(4)
// The A prefetch (HBM, ~900 cy) stays in flight across the MFMA block and
// into the next iteration. Never vmcnt(0) in the main loop.
//
// Fragment layout (verified R1 of prior session, absmax 0.125):
//   A frag: lane holds A[m0 + (lane&15)][32*kk + (lane>>4)*8 + j], j=0..7
//   B frag: lane holds Wt[n0 + (lane&15)][32*kk + (lane>>4)*8 + j]
//   D frag: D[m0 + (lane>>4)*4 + rr][n0 + (lane&15)], rr=0..3
// ---------------------------------------------------------------------------
__global__ __launch_bounds__(256, 4)
void sampling_gemm(const float* __restrict__ x,
                   const __hip_bfloat16* __restrict__ wt,
                   float* __restrict__ out) {
    const int lane = threadIdx.x & 63;
    const int wave = threadIdx.x >> 6;                    // 0..3
    const int r    = lane & 15;
    const int q    = lane >> 4;                           // quad 0..3

    const long m0 = (long)blockIdx.x * 128 + (long)wave * 32;

    const float* a0 = x + (m0 + r) * DENSE_L + q * 8;     // m-subtile 0 row
    const float* a1 = a0 + 16 * DENSE_L;                  // m-subtile 1 row
    const short* w0 = (const short*)wt + r * DENSE_L + q * 8;

    float4v acc[2][4];
    #pragma unroll
    for (int i = 0; i < 2; ++i)
        #pragma unroll
        for (int j = 0; j < 4; ++j)
            acc[i][j] = (float4v){0.f, 0.f, 0.f, 0.f};

    // prefetch slab 0 of A
    float4v c0a = ldnt(a0), c0b = ldnt(a0 + 4);
    float4v c1a = ldnt(a1), c1b = ldnt(a1 + 4);

    for (int kk = 0; kk < 32; ++kk) {
        // (1) B-fragment loads for THIS slab — issued first so their wait is
        // a counted vmcnt(4), not a drain (see header comment).
        const short* wk = w0 + kk * 32;
        const short8 b0 = *(const short8*)(wk);
        const short8 b1 = *(const short8*)(wk + 16 * DENSE_L);
        const short8 b2 = *(const short8*)(wk + 32 * DENSE_L);
        const short8 b3 = *(const short8*)(wk + 48 * DENSE_L);

        // (2) depth-1 A prefetch for the NEXT slab — newest in the vmcnt
        // FIFO, so it is never waited on this iteration.
        const int kn = (kk + 1) & 31;                     // wraps: harmless reload
        const float4v n0a = ldnt(a0 + kn * 32);
        const float4v n0b = ldnt(a0 + kn * 32 + 4);
        const float4v n1a = ldnt(a1 + kn * 32);
        const float4v n1b = ldnt(a1 + kn * 32 + 4);

        // (3) convert current A (waits vmcnt(8): curA done, B+nextA in flight)
        const short8 af0 = cvt8(c0a, c0b);
        const short8 af1 = cvt8(c1a, c1b);

        // (4) MFMAs (wait vmcnt(4): B done, nextA still in flight)
        acc[0][0] = __builtin_amdgcn_mfma_f32_16x16x32_bf16(af0, b0, acc[0][0], 0, 0, 0);
        acc[1][0] = __builtin_amdgcn_mfma_f32_16x16x32_bf16(af1, b0, acc[1][0], 0, 0, 0);
        acc[0][1] = __builtin_amdgcn_mfma_f32_16x16x32_bf16(af0, b1, acc[0][1], 0, 0, 0);
        acc[1][1] = __builtin_amdgcn_mfma_f32_16x16x32_bf16(af1, b1, acc[1][1], 0, 0, 0);
        acc[0][2] = __builtin_amdgcn_mfma_f32_16x16x32_bf16(af0, b2, acc[0][2], 0, 0, 0);
        acc[1][2] = __builtin_amdgcn_mfma_f32_16x16x32_bf16(af1, b2, acc[1][2], 0, 0, 0);
        acc[0][3] = __builtin_amdgcn_mfma_f32_16x16x32_bf16(af0, b3, acc[0][3], 0, 0, 0);
        acc[1][3] = __builtin_amdgcn_mfma_f32_16x16x32_bf16(af1, b3, acc[1][3], 0, 0, 0);

        c0a = n0a; c0b = n0b; c1a = n1a; c1b = n1b;
    }

    // Epilogue: D[m = q*4 + rr][n = ns*16 + r]; streaming stores.
    #pragma unroll
    for (int ms = 0; ms < 2; ++ms) {
        #pragma unroll
        for (int ns = 0; ns < 4; ++ns) {
            #pragma unroll
            for (int rr = 0; rr < 4; ++rr) {
                __builtin_nontemporal_store(
                    acc[ms][ns][rr],
                    out + (m0 + ms * 16 + q * 4 + rr) * L_TILDE + ns * 16 + r);
            }
        }
    }
}

// ---------------------------------------------------------------------------
extern "C" void kernel_launch(void* const* d_in, const int* in_sizes, int n_in,
                              void* d_out, int out_size, void* d_ws, size_t ws_size,
                              hipStream_t stream) {
    const float* x      = (const float*)d_in[0];   // [B, P*L] fp32
    const float* weight = (const float*)d_in[1];   // [64] fp32
    float* out          = (float*)d_out;           // [B, P*64] fp32
    __hip_bfloat16* wt  = (__hip_bfloat16*)d_ws;   // [64][1024] bf16 = 128 KiB

    const int M = in_sizes[0] / DENSE_L;           // B * NUM_ADC_P = 131072
    const int grid = M / 128;                      // 128 rows per block

    build_w<<<64, 256, 0, stream>>>(weight, wt);
    sampling_gemm<<<grid, 256, 0, stream>>>(x, wt, out);
}